// Round 1
// baseline (146.629 us; speedup 1.0000x reference)
//
#include <hip/hip_runtime.h>
#include <math.h>

// Problem constants (from reference)
#define BB   4
#define NN   40
#define TT   64
#define NIN  4
#define NEMB 32
#define NHID 64
#define NG   256   // 4*NHID
#define EPSW 1e-5f

// ---------------------------------------------------------------------------
// Kernel 1: per-(b,n) LSTM chain + temporal-attention pooling (output cols 0..63)
// Also stores hs[t][h] to global workspace for kernel 2.
// Grid: 160 blocks (b*40+n), 256 threads (one per gate row).
// ---------------------------------------------------------------------------
__global__ __launch_bounds__(256)
void k_lstm(const float* __restrict__ inputs,
            const float* __restrict__ W_emb,
            const float* __restrict__ b_emb,
            const float* __restrict__ W_ih,
            const float* __restrict__ W_hh,
            const float* __restrict__ b_ih,
            const float* __restrict__ b_hh,
            const float* __restrict__ W_att,
            float* __restrict__ out,
            float* __restrict__ hs_g)
{
    __shared__ __align__(16) float s_x[TT * NIN];          // raw inputs for this (b,n)
    __shared__ __align__(16) float s_emb[TT * NEMB];       // embedded sequence
    __shared__ __align__(16) float s_act[NG];              // gate activations, one step
    __shared__ __align__(16) float s_h[NHID];              // current hidden state
    __shared__ __align__(16) float s_hs[TT * (NHID + 1)];  // all hidden states, pad 65 (bank-conflict-free)
    __shared__ __align__(16) float s_war[NHID];            // W_att[0, 64:128]
    __shared__ __align__(16) float s_p[TT];                // softmax weights

    const int m   = blockIdx.x;       // b*NN + n
    const int tid = threadIdx.x;
    const int g   = tid;              // gate row 0..255
    const int gtype = g >> 6;         // 0:i 1:f 2:g 3:o  (wave-uniform)

    // stage raw inputs (256 floats, coalesced)
    s_x[tid] = inputs[m * (TT * NIN) + tid];
    if (tid < NHID) s_war[tid] = W_att[NHID + tid];
    __syncthreads();

    // embedding: emb[t][e] = b_emb[e] + sum_i x[t][i] * W_emb[e][i]
    for (int idx = tid; idx < TT * NEMB; idx += 256) {
        const int t = idx >> 5;
        const int e = idx & 31;
        float v = b_emb[e];
        #pragma unroll
        for (int i = 0; i < NIN; ++i)
            v += s_x[t * NIN + i] * W_emb[e * NIN + i];
        s_emb[idx] = v;
    }

    // load this thread's gate-row weights into registers
    float wih[NEMB];
    float whh[NHID];
    {
        const float4* p4 = (const float4*)(W_ih + g * NEMB);
        #pragma unroll
        for (int k = 0; k < NEMB / 4; ++k) {
            float4 v = p4[k];
            wih[4 * k + 0] = v.x; wih[4 * k + 1] = v.y;
            wih[4 * k + 2] = v.z; wih[4 * k + 3] = v.w;
        }
        const float4* q4 = (const float4*)(W_hh + g * NHID);
        #pragma unroll
        for (int k = 0; k < NHID / 4; ++k) {
            float4 v = q4[k];
            whh[4 * k + 0] = v.x; whh[4 * k + 1] = v.y;
            whh[4 * k + 2] = v.z; whh[4 * k + 3] = v.w;
        }
    }
    const float bias = b_ih[g] + b_hh[g];

    if (tid < NHID) s_h[tid] = 0.0f;
    float c = 0.0f;
    __syncthreads();

    // ------------------- recurrence: 64 sequential steps -------------------
    for (int t = 0; t < TT; ++t) {
        // gate pre-activation: bias + emb[t] . wih + h . whh   (4 indep chains)
        float v0 = bias, v1 = 0.f, v2 = 0.f, v3 = 0.f;
        const float4* e4 = (const float4*)(s_emb + t * NEMB);
        #pragma unroll
        for (int k = 0; k < NEMB / 4; ++k) {
            float4 a = e4[k];
            v0 += a.x * wih[4 * k + 0];
            v1 += a.y * wih[4 * k + 1];
            v2 += a.z * wih[4 * k + 2];
            v3 += a.w * wih[4 * k + 3];
        }
        const float4* h4 = (const float4*)s_h;
        #pragma unroll
        for (int k = 0; k < NHID / 4; ++k) {
            float4 a = h4[k];
            v0 += a.x * whh[4 * k + 0];
            v1 += a.y * whh[4 * k + 1];
            v2 += a.z * whh[4 * k + 2];
            v3 += a.w * whh[4 * k + 3];
        }
        const float v = (v0 + v1) + (v2 + v3);

        // activation (branch is wave-uniform: wave 2 = tanh, others sigmoid)
        float a;
        if (gtype == 2) a = tanhf(v);
        else            a = 1.0f / (1.0f + expf(-v));
        s_act[g] = a;
        __syncthreads();

        if (tid < NHID) {
            const float ig = s_act[tid];
            const float fg = s_act[NHID + tid];
            const float gg = s_act[2 * NHID + tid];
            const float og = s_act[3 * NHID + tid];
            c = fg * c + ig * gg;
            const float h = og * tanhf(c);
            s_h[tid] = h;
            s_hs[t * (NHID + 1) + tid] = h;
            hs_g[(m * TT + t) * NHID + tid] = h;   // coalesced 256B
        }
        __syncthreads();
    }

    // ------------------- temporal attention pooling -------------------
    // softmax over t of r[t] = hs[t] . W_att[0,64:128]  (i-independent: the
    // sender term and b_att are constant across the softmax axis)
    if (tid < TT) {
        const int t = tid;
        float r = 0.0f;
        #pragma unroll
        for (int k = 0; k < NHID; ++k)
            r += s_hs[t * (NHID + 1) + k] * s_war[k];
        float mx = r;
        #pragma unroll
        for (int off = 32; off >= 1; off >>= 1)
            mx = fmaxf(mx, __shfl_xor(mx, off));
        const float e = expf(r - mx);
        float s = e;
        #pragma unroll
        for (int off = 32; off >= 1; off >>= 1)
            s += __shfl_xor(s, off);
        s_p[t] = e / s;
    }
    __syncthreads();

    if (tid < NHID) {
        const int h = tid;
        float acc = 0.0f;
        #pragma unroll
        for (int t = 0; t < TT; ++t)
            acc += s_p[t] * s_hs[t * (NHID + 1) + h];
        out[m * (2 * NHID) + h] = tanhf(acc);
    }
}

// ---------------------------------------------------------------------------
// Kernel 2: spatial inverse-distance aggregation (output cols 64..127)
// chsum[b,i,h] = sum_t sum_{j!=i} hs[b,j,t,h] / (dist(i,j,t)+eps)
// Grid: 160 blocks (b*40+i), 256 threads = (t-quarter q, h).
// ---------------------------------------------------------------------------
__global__ __launch_bounds__(256)
void k_spatial(const float* __restrict__ inputs,
               const float* __restrict__ hs_g,
               float* __restrict__ out)
{
    __shared__ float s_w[TT * NN];          // 2560 inverse-distance weights
    __shared__ float s_part[4 * NHID];

    const int bi  = blockIdx.x;
    const int b   = bi / NN;
    const int i   = bi - b * NN;
    const int tid = threadIdx.x;

    // w[t][j] = (j==i) ? 0 : 1/(||loc_i - loc_j||+eps) from raw inputs
    for (int idx = tid; idx < TT * NN; idx += 256) {
        const int t = idx / NN;
        const int j = idx - t * NN;
        const float* pi = inputs + ((b * NN + i) * TT + t) * NIN;
        const float* pj = inputs + ((b * NN + j) * TT + t) * NIN;
        const float dx = pi[0] - pj[0];
        const float dy = pi[1] - pj[1];
        const float d  = sqrtf(dx * dx + dy * dy);
        s_w[idx] = (j == i) ? 0.0f : 1.0f / (d + EPSW);
    }
    __syncthreads();

    const int h = tid & 63;
    const int q = tid >> 6;          // t-quarter

    // hs_g[((b*NN + j)*TT + t)*NHID + h]
    const float* base = hs_g + (size_t)b * NN * TT * NHID + h;
    float a0 = 0.f, a1 = 0.f, a2 = 0.f, a3 = 0.f;
    for (int t = q * 16; t < q * 16 + 16; ++t) {
        const float* hp = base + t * NHID;
        const float* wp = s_w + t * NN;
        #pragma unroll
        for (int j = 0; j < NN; j += 4) {
            a0 += wp[j + 0] * hp[(size_t)(j + 0) * TT * NHID];
            a1 += wp[j + 1] * hp[(size_t)(j + 1) * TT * NHID];
            a2 += wp[j + 2] * hp[(size_t)(j + 2) * TT * NHID];
            a3 += wp[j + 3] * hp[(size_t)(j + 3) * TT * NHID];
        }
    }
    s_part[q * NHID + h] = (a0 + a1) + (a2 + a3);
    __syncthreads();

    if (tid < NHID) {
        const float s = s_part[tid] + s_part[NHID + tid] +
                        s_part[2 * NHID + tid] + s_part[3 * NHID + tid];
        out[bi * (2 * NHID) + NHID + tid] = tanhf(s);
    }
}

extern "C" void kernel_launch(void* const* d_in, const int* in_sizes, int n_in,
                              void* d_out, int out_size, void* d_ws, size_t ws_size,
                              hipStream_t stream) {
    const float* inputs = (const float*)d_in[0];
    // d_in[1..4] are rel_rec / rel_send / rel_rec_t / rel_send_t (one-hot,
    // structure folded into the kernels analytically)
    const float* W_emb  = (const float*)d_in[5];
    const float* b_emb  = (const float*)d_in[6];
    const float* W_ih   = (const float*)d_in[7];
    const float* W_hh   = (const float*)d_in[8];
    const float* b_ih   = (const float*)d_in[9];
    const float* b_hh   = (const float*)d_in[10];
    const float* W_att  = (const float*)d_in[11];
    // d_in[12] = b_att: cancels in the softmax, unused.

    float* outp = (float*)d_out;
    float* hs_g = (float*)d_ws;   // 160*64*64 floats = 2.62 MB

    hipLaunchKernelGGL(k_lstm, dim3(BB * NN), dim3(256), 0, stream,
                       inputs, W_emb, b_emb, W_ih, W_hh, b_ih, b_hh, W_att,
                       outp, hs_g);
    hipLaunchKernelGGL(k_spatial, dim3(BB * NN), dim3(256), 0, stream,
                       inputs, hs_g, outp);
}